// Round 3
// baseline (339.967 us; speedup 1.0000x reference)
//
#include <hip/hip_runtime.h>
#include <hip/hip_bf16.h>
#include <stdint.h>

// Problem constants
#define N_PATCH 3136     // 56*56 query rows
#define N_PATCH_PAD 3328 // 13 m-tiles * 256
#define N_LIB   16384    // memory bank rows
#define DIM     768
#define IMGSZ   224
#define FM      56

// GEMM tiling: 256x256 tile, BK=32, 8 waves (2M x 4N), 4-deep LDS ring
#define TILE 256
#define BK 32
#define KT 24            // DIM/BK
#define MT 13            // ceil(3136/256) m-tiles
#define NTILES 64        // 16384/256 n-tiles
#define NWORK (MT * NTILES)   // 832 tile-pairs
#define GEMMB 256        // persistent blocks (1/CU by LDS), atomic work queue

// tail kernel: 64 blocks <= 256 CUs -> always co-resident (manual grid barrier safe)
#define TAILB 64
#define D2_MARGIN 8.0f   // ~24 sigma of bf16 d2 noise: tiles within this of best get fp32 rescan

typedef __bf16 bf16_t;
typedef __bf16 bf16x8 __attribute__((ext_vector_type(8)));
typedef __bf16 bf16x4_v __attribute__((ext_vector_type(4)));
typedef float  f32x4  __attribute__((ext_vector_type(4)));

#define FLT_MAX_ 3.402823466e+38f

struct Scal {
  unsigned long long approx_max_pack;   // (bits(sqrt-min)<<32) | (0xffffffff - row)
  unsigned long long cand_pack[64];     // per-candidate exact (bits(d2)<<32)|argmin_j
  int cand[64];
  int cand_count;
  int bar[4];                           // grid-barrier counters (one-shot each)
  int work;                             // gemm persistent work queue head
};

__device__ __forceinline__ float wave_reduce_sum(float v) {
#pragma unroll
  for (int s = 32; s > 0; s >>= 1) v += __shfl_xor(v, s, 64);
  return v;
}

__device__ __forceinline__ float wave_reduce_min(float v) {
#pragma unroll
  for (int s = 32; s > 0; s >>= 1) v = fminf(v, __shfl_xor(v, s, 64));
  return v;
}

__device__ __forceinline__ unsigned long long shfl_xor_u64(unsigned long long v, int mask) {
  unsigned lo = (unsigned)v, hi = (unsigned)(v >> 32);
  lo = __shfl_xor(lo, mask, 64);
  hi = __shfl_xor(hi, mask, 64);
  return ((unsigned long long)hi << 32) | lo;
}

// async global->LDS, 16B per lane; LDS dest = wave-uniform base + lane*size
__device__ __forceinline__ void async16(const bf16_t* g, bf16_t* l) {
  __builtin_amdgcn_global_load_lds(
      (const __attribute__((address_space(1))) unsigned int*)g,
      (__attribute__((address_space(3))) unsigned int*)l, 16, 0, 0);
}

// software grid barrier (rocPRIM pattern); REQUIRES all blocks co-resident.
__device__ __forceinline__ void grid_bar(int* ctr, int nb) {
  __syncthreads();
  if (threadIdx.x == 0) {
    __threadfence();
    atomicAdd(ctr, 1);
    while (atomicAdd(ctr, 0) < nb) __builtin_amdgcn_s_sleep(8);
    __threadfence();
  }
  __syncthreads();
}

__device__ __forceinline__ float bf16u_to_f(unsigned short u) {
  return __uint_as_float(((unsigned)u) << 16);
}

// ------------------------------------------------- prep: normalize + bf16 + norms
__global__ void prep_kernel(const float* __restrict__ patch, const float* __restrict__ lib,
                            const float* __restrict__ meanp, const float* __restrict__ stdp,
                            bf16_t* __restrict__ pb, bf16_t* __restrict__ lb,
                            float* __restrict__ a2, float* __restrict__ b2, Scal* sc) {
  int t = threadIdx.x;
  int lane = t & 63;
  if (blockIdx.x == 0) {
    if (t < 64) sc->cand_pack[t] = ~0ULL;
    if (t == 64) { sc->approx_max_pack = 0ULL; sc->cand_count = 0; }
    if (t >= 65 && t < 69) sc->bar[t - 65] = 0;
    if (t == 69) sc->work = 0;
  }
  if (blockIdx.x < N_PATCH / 4) {
    int row = blockIdx.x * 4 + (t >> 6);
    float mu = meanp[0], sd = stdp[0];
    float acc = 0.f;
#pragma unroll
    for (int k = 0; k < 3; k++) {
      float4 v = ((const float4*)(patch + (size_t)row * DIM))[lane + 64 * k];
      v.x = (v.x - mu) / sd; v.y = (v.y - mu) / sd;
      v.z = (v.z - mu) / sd; v.w = (v.w - mu) / sd;
      bf16x4_v o = {(__bf16)v.x, (__bf16)v.y, (__bf16)v.z, (__bf16)v.w};
      *(bf16x4_v*)(pb + (size_t)row * DIM + (lane + 64 * k) * 4) = o;
      acc += v.x*v.x + v.y*v.y + v.z*v.z + v.w*v.w;
    }
    acc = wave_reduce_sum(acc);
    if (lane == 0) a2[row] = acc;
  } else {
    int row = (blockIdx.x - N_PATCH / 4) * 4 + (t >> 6);
    float acc = 0.f;
#pragma unroll
    for (int k = 0; k < 3; k++) {
      float4 v = ((const float4*)(lib + (size_t)row * DIM))[lane + 64 * k];
      bf16x4_v o = {(__bf16)v.x, (__bf16)v.y, (__bf16)v.z, (__bf16)v.w};
      *(bf16x4_v*)(lb + (size_t)row * DIM + (lane + 64 * k) * 4) = o;
      acc += v.x*v.x + v.y*v.y + v.z*v.z + v.w*v.w;
    }
    acc = wave_reduce_sum(acc);
    if (lane == 0) b2[row] = acc;
  }
}

// ------------------------------------------------- fused bf16 GEMM + row-min
// Persistent 256-block grid, atomic work queue over 832 (mtile,ntile) pairs.
// Per tile: 256x256, BK=32, 8 waves (2Mx4N), 4-deep LDS ring, counted vmcnt +
// raw s_barrier (T3/T4), conflict-free swizzled LDS (T2), and per-K-step
// TWO-PHASE fine interleave (template ratios: per phase {4-8 ds_read || 2
// global_load_lds -> barrier -> 16 MFMA (setprio, T5) -> barrier}).
//
// LDS layout (per 16KB tile): row-PAIR lines of 128B = 8 slots x 16B.
//   stored slot s for (row r, kchunk kc in [0,4)): s = (((r&1)<<2)|kc) ^ ((r>>1)&7)
//   Frag read: addr = R0*64 + (l15>>1)*128 + (((((l15&1)<<2)|quad) ^ (l15>>1)) << 4)
//   => each quarter-wave hits every 16B slot exactly 2x: 2-way = free [m136].
//   global_load_lds writes LINEAR dest; the involution is applied to the
//   global SOURCE address instead (rule #21: both-sides-or-neither).
//
// Pipeline (per wave, 4 global_load_lds per staged K-tile; A-half issued in
// phase 0, B-half in phase 1 -> per-wave FIFO stays 4 loads per tile):
//   loop-top iter k: outstanding = tiles {k,k+1,k+2} = 12 loads
//   vmcnt(8) -> tile k fully landed (all waves then barrier before ds_read,
//   since any wave may read bytes staged by another wave's loads).
//   stage(k+3) reuses slot (k-1)&3: all waves' iter-(k-1) ds_reads completed
//   (reg-dep lgkmcnt before their MFMAs) before they passed the iter-k top
//   barrier -> no WAR race. Iter-(k+1)'s stage(k+4) -> slot k&3 is likewise
//   fenced from iter-k P1 reads by iter-(k+1)'s top barrier.
__global__ __launch_bounds__(512, 2)
void gemm_min_kernel(const bf16_t* __restrict__ pb, const bf16_t* __restrict__ lb,
                     const float* __restrict__ a2, const float* __restrict__ b2,
                     float* __restrict__ part, Scal* __restrict__ sc) {
  __shared__ __align__(16) bf16_t As[4][TILE * BK];   // 64 KiB
  __shared__ __align__(16) bf16_t Bs[4][TILE * BK];   // 64 KiB  -> 128 KiB total
  __shared__ int sw;

  const int t = threadIdx.x;
  const int wave = t >> 6;
  const int lane = t & 63;
  const int l15 = lane & 15;
  const int quad = lane >> 4;
  const int wm = (wave >> 2) * 128;    // wave_m in {0,1}
  const int wn = (wave & 3) * 64;      // wave_n in {0..3}

  // ---- staging source map: dest chunk c (16B units) -> logical (row, kchunk)
  // dest line L=c>>3, slot s=c&7; slog = s ^ (L&7); r = 2L + (slog>>2); kc = slog&3
  int rA0, kA0, rA1, kA1;
  {
    int c = t, L = c >> 3, s = c & 7, g = s ^ (L & 7);
    rA0 = 2 * L + (g >> 2); kA0 = g & 3;
    c = t + 512; L = c >> 3; s = c & 7; g = s ^ (L & 7);
    rA1 = 2 * L + (g >> 2); kA1 = g & 3;
  }

  // per-lane invariant fragment-read byte offset (see header comment)
  const int off_lane = (l15 >> 1) * 128 + (((((l15 & 1) << 2) | quad) ^ (l15 >> 1)) << 4);

  for (;;) {
    if (t == 0) sw = atomicAdd(&sc->work, 1);
    __syncthreads();                    // also fences prior tile's smin reads
    const int w = sw;
    if (w >= NWORK) break;

    const int ntile = w / MT;
    const int mtile = w - ntile * MT;
    const int m0 = mtile * TILE;
    const int n0 = ntile * TILE;

    int raA0 = m0 + rA0;        if (raA0 > N_PATCH - 1) raA0 = N_PATCH - 1;
    int raA1 = m0 + rA1;        if (raA1 > N_PATCH - 1) raA1 = N_PATCH - 1;
    const bf16_t* gA0 = pb + (size_t)raA0 * DIM + kA0 * 8;
    const bf16_t* gA1 = pb + (size_t)raA1 * DIM + kA1 * 8;
    const bf16_t* gB0 = lb + (size_t)(n0 + rA0) * DIM + kA0 * 8;
    const bf16_t* gB1 = lb + (size_t)(n0 + rA1) * DIM + kA1 * 8;

    f32x4 acc[8][4];
#pragma unroll
    for (int mi = 0; mi < 8; mi++)
#pragma unroll
      for (int ni = 0; ni < 4; ni++) { f32x4 z = {0.f,0.f,0.f,0.f}; acc[mi][ni] = z; }

    // prologue: fill 3 ring slots (4 loads each, A0,A1,B0,B1 order)
#pragma unroll
    for (int p = 0; p < 3; p++) {
      const size_t ko = (size_t)p * BK;
      async16(gA0 + ko, &As[p][0] + (size_t)t * 8);
      async16(gA1 + ko, &As[p][0] + 4096 + (size_t)t * 8);
      async16(gB0 + ko, &Bs[p][0] + (size_t)t * 8);
      async16(gB1 + ko, &Bs[p][0] + 4096 + (size_t)t * 8);
    }

    // one K-step: two fine-interleaved phases. kst = tile to stage (or -1).
    auto kstep = [&](int s, int kst) {
      const char* Ab = (const char*)(&As[s][0]);
      const char* Bb = (const char*)(&Bs[s][0]);
      // ---- phase 0: read B-frags + low A-frags, issue A-half stage
      bf16x8 bfr[4], afr[4];
#pragma unroll
      for (int ni = 0; ni < 4; ni++)
        bfr[ni] = *(const bf16x8*)(Bb + (wn + ni * 16) * 64 + off_lane);
#pragma unroll
      for (int mi = 0; mi < 4; mi++)
        afr[mi] = *(const bf16x8*)(Ab + (wm + mi * 16) * 64 + off_lane);
      if (kst >= 0) {
        const size_t ko = (size_t)kst * BK;
        bf16_t* dst = &As[kst & 3][0];
        async16(gA0 + ko, dst + (size_t)t * 8);
        async16(gA1 + ko, dst + 4096 + (size_t)t * 8);
      }
      asm volatile("" ::: "memory");
      __builtin_amdgcn_s_barrier();
      __builtin_amdgcn_s_setprio(1);
#pragma unroll
      for (int mi = 0; mi < 4; mi++)
#pragma unroll
        for (int ni = 0; ni < 4; ni++)
          acc[mi][ni] = __builtin_amdgcn_mfma_f32_16x16x32_bf16(afr[mi], bfr[ni],
                                                                acc[mi][ni], 0, 0, 0);
      __builtin_amdgcn_s_setprio(0);
      __builtin_amdgcn_s_barrier();
      // ---- phase 1: read high A-frags, issue B-half stage
      bf16x8 afr2[4];
#pragma unroll
      for (int mi = 0; mi < 4; mi++)
        afr2[mi] = *(const bf16x8*)(Ab + (wm + 64 + mi * 16) * 64 + off_lane);
      if (kst >= 0) {
        const size_t ko = (size_t)kst * BK;
        bf16_t* dst = &Bs[kst & 3][0];
        async16(gB0 + ko, dst + (size_t)t * 8);
        async16(gB1 + ko, dst + 4096 + (size_t)t * 8);
      }
      asm volatile("" ::: "memory");
      __builtin_amdgcn_s_barrier();
      __builtin_amdgcn_s_setprio(1);
#pragma unroll
      for (int mi = 0; mi < 4; mi++)
#pragma unroll
        for (int ni = 0; ni < 4; ni++)
          acc[4 + mi][ni] = __builtin_amdgcn_mfma_f32_16x16x32_bf16(afr2[mi], bfr[ni],
                                                                    acc[4 + mi][ni], 0, 0, 0);
      __builtin_amdgcn_s_setprio(0);
      // phase-1 closing barrier = next K-step's top barrier
    };

    for (int k = 0; k < KT - 3; ++k) {
      asm volatile("s_waitcnt vmcnt(8)" ::: "memory");
      __builtin_amdgcn_s_barrier();
      asm volatile("" ::: "memory");
      kstep(k & 3, k + 3);
    }
    asm volatile("s_waitcnt vmcnt(8)" ::: "memory");
    __builtin_amdgcn_s_barrier();
    asm volatile("" ::: "memory");
    kstep((KT - 3) & 3, -1);

    asm volatile("s_waitcnt vmcnt(4)" ::: "memory");
    __builtin_amdgcn_s_barrier();
    asm volatile("" ::: "memory");
    kstep((KT - 2) & 3, -1);

    asm volatile("s_waitcnt vmcnt(0)" ::: "memory");
    __builtin_amdgcn_s_barrier();
    asm volatile("" ::: "memory");
    kstep((KT - 1) & 3, -1);

    // ---- epilogue: d2 = a2 + b2 - 2ab, row-min, cross-wave via smin (reuses As) ----
    __syncthreads();
    unsigned* smin = (unsigned*)&As[0][0];
    if (t < 256) smin[t] = 0xffffffffu;
    __syncthreads();

    float b2n[4];
#pragma unroll
    for (int ni = 0; ni < 4; ni++) b2n[ni] = b2[n0 + wn + ni * 16 + l15];

#pragma unroll
    for (int mi = 0; mi < 8; mi++) {
#pragma unroll
      for (int r = 0; r < 4; r++) {
        int rloc = wm + mi * 16 + quad * 4 + r;
        int mrow = m0 + rloc;
        float a2v = a2[mrow < N_PATCH ? mrow : (N_PATCH - 1)];
        // C/D layout: col = lane&15, row = quad*4 + reg  [m89/m91]
        float best = a2v + b2n[0] - 2.0f * acc[mi][0][r];
#pragma unroll
        for (int ni = 1; ni < 4; ni++)
          best = fminf(best, a2v + b2n[ni] - 2.0f * acc[mi][ni][r]);
        best = fmaxf(best, 0.0f);
#pragma unroll
        for (int s = 1; s < 16; s <<= 1)
          best = fminf(best, __shfl_xor(best, s, 64));
        if (l15 == 0) atomicMin(&smin[rloc], __float_as_uint(best));
      }
    }
    __syncthreads();
    if (t < 256) part[(size_t)ntile * N_PATCH_PAD + m0 + t] = __uint_as_float(smin[t]);
    // next work-fetch __syncthreads() fences smin reads vs. next prologue stages
  }
}

// inline "pick": wave-level max over candidates
__device__ __forceinline__ void wave_pick(const Scal* sc, int cnt, int lane,
                                          int* srow, float* sstar, int* ms) {
  unsigned long long pk = 0ULL;
  int rowv = 0, msv = 0;
  if (lane < cnt) {
    unsigned long long cp = sc->cand_pack[lane];
    rowv = sc->cand[lane];
    msv = (int)(cp & 0xffffffffu);
    pk = (cp & 0xffffffff00000000ULL) | (unsigned)(0xffffffffu - (unsigned)rowv);
  }
  unsigned long long m = pk;
#pragma unroll
  for (int s = 1; s < 64; s <<= 1) {
    unsigned long long o = shfl_xor_u64(m, s);
    if (o > m) m = o;
  }
  unsigned long long mask = __ballot(pk == m && lane < cnt);
  int wl = (int)(__ffsll((long long)mask) - 1);
  *srow = __shfl(rowv, wl, 64);
  *ms   = __shfl(msv, wl, 64);
  *sstar = sqrtf(__uint_as_float((unsigned)(m >> 32)));
}

// ------------------------------------------------- tail (single dispatch, 64 blocks):
// P0 finalize -> bar -> P1 collect -> bar -> P2 tile-targeted fp32 refine -> bar ->
// P3 wdist (bf16, selection only) -> bar -> P4 (top3+s on block 0 || resize+blur 1..49)
__global__ __launch_bounds__(256, 2)
void tail_kernel(const float* __restrict__ part, float* __restrict__ min_val,
                 const float* __restrict__ patch, const float* __restrict__ lib,
                 const bf16_t* __restrict__ lb,
                 const float* __restrict__ meanp, const float* __restrict__ stdp,
                 Scal* __restrict__ sc, float* __restrict__ wdist2,
                 float* __restrict__ out0, float* __restrict__ outmap) {
  __shared__ union {
    unsigned long long sl[768];   // top3
    float rs[40 * 40];            // resize halo
  } sm;
  __shared__ float redbuf[4];
  __shared__ int s_cnt;

  const int t = threadIdx.x;
  const int b = blockIdx.x;
  const int wave = t >> 6, lane = t & 63;

  // ---- P0: finalize (blocks 0..12 cover 3136 rows; coalesced column reads) ----
  {
    int row = b * 256 + t;
    if (row < N_PATCH) {
      float m = FLT_MAX_;
#pragma unroll 8
      for (int nt = 0; nt < NTILES; nt++)
        m = fminf(m, part[(size_t)nt * N_PATCH_PAD + row]);
      float v = sqrtf(m);
      min_val[row] = v;
      unsigned long long mp = (((unsigned long long)__float_as_uint(v)) << 32) |
                              (unsigned)(0xffffffffu - (unsigned)row);  // ties -> smaller row
      atomicMax(&sc->approx_max_pack, mp);
    }
  }
  grid_bar(&sc->bar[0], TAILB);

  // ---- P1: collect candidates (block 0; margin 0.05 ~ 10 sigma of bf16 dist noise) ----
  if (b == 0) {
    float amax = __uint_as_float((unsigned)(atomicMax(&sc->approx_max_pack, 0ULL) >> 32));
    for (int i = t; i < N_PATCH; i += 256) {
      if (min_val[i] >= amax - 0.05f) {
        int p = atomicAdd(&sc->cand_count, 1);
        if (p < 64) sc->cand[p] = i;
      }
    }
  }
  grid_bar(&sc->bar[1], TAILB);

  if (t == 0) s_cnt = atomicAdd(&sc->cand_count, 0);
  __syncthreads();
  int cnt = s_cnt; if (cnt > 64) cnt = 64;

  // ---- P2: tile-targeted exact refine. Block b owns ntile b (256 lib rows).
  // Only tiles whose bf16 partial min is within D2_MARGIN of the row's global
  // partial min get a 256-row fp32 rescan (true argmin provably inside margin).
  {
    float mu = meanp[0], sd = stdp[0];
    for (int c = 0; c < cnt; c++) {
      int row = sc->cand[c];
      // block-wide min over all 64 partials for this row
      float pv_ = (t < NTILES) ? part[(size_t)t * N_PATCH_PAD + row] : FLT_MAX_;
      pv_ = wave_reduce_min(pv_);
      if (lane == 0) redbuf[wave] = pv_;
      __syncthreads();
      float bmin = fminf(fminf(redbuf[0], redbuf[1]), fminf(redbuf[2], redbuf[3]));
      __syncthreads();

      float4 pv[3];
#pragma unroll
      for (int k = 0; k < 3; k++) {
        float4 v = ((const float4*)(patch + (size_t)row * DIM))[lane + 64 * k];
        v.x = (v.x - mu) / sd; v.y = (v.y - mu) / sd;
        v.z = (v.z - mu) / sd; v.w = (v.w - mu) / sd;
        pv[k] = v;
      }
      int nt = b;
      float pmin = part[(size_t)nt * N_PATCH_PAD + row];   // uniform -> broadcast
      if (pmin <= bmin + D2_MARGIN) {
        unsigned long long best = ~0ULL;
        int jb = nt * 256 + wave * 64;
        for (int rr = 0; rr < 64; rr++) {
          int j = jb + rr;
          const float4* pl = (const float4*)(lib + (size_t)j * DIM);
          float acc = 0.f;
#pragma unroll
          for (int k = 0; k < 3; k++) {
            float4 l = pl[lane + 64 * k];
            float dx = pv[k].x - l.x, dy = pv[k].y - l.y;
            float dz = pv[k].z - l.z, dw = pv[k].w - l.w;
            acc += dx*dx + dy*dy + dz*dz + dw*dw;
          }
          acc = wave_reduce_sum(acc);
          unsigned long long pk = (((unsigned long long)__float_as_uint(acc)) << 32) | (unsigned)j;
          if (pk < best) best = pk;
        }
        if (lane == 0) atomicMin(&sc->cand_pack[c], best);
      }
    }
  }
  grid_bar(&sc->bar[2], TAILB);

  // ---- P3: wdist on bf16 lb (selection only; exact d's recomputed in P4a) ----
  {
    int srow_, ms; float ss_;
    wave_pick(sc, cnt, lane, &srow_, &ss_, &ms);
    float pm[12];
    const ushort4* pms = (const ushort4*)(lb + (size_t)ms * DIM);
#pragma unroll
    for (int k = 0; k < 3; k++) {
      ushort4 u = pms[lane + 64 * k];
      pm[k*4+0] = bf16u_to_f(u.x); pm[k*4+1] = bf16u_to_f(u.y);
      pm[k*4+2] = bf16u_to_f(u.z); pm[k*4+3] = bf16u_to_f(u.w);
    }
    int jbase = b * 256 + wave * 64;
    for (int rr = 0; rr < 64; rr += 2) {
      int j0 = jbase + rr, j1 = j0 + 1;
      const ushort4* r0 = (const ushort4*)(lb + (size_t)j0 * DIM);
      const ushort4* r1 = (const ushort4*)(lb + (size_t)j1 * DIM);
      float a0 = 0.f, a1 = 0.f;
#pragma unroll
      for (int k = 0; k < 3; k++) {
        ushort4 u0 = r0[lane + 64 * k];
        ushort4 u1 = r1[lane + 64 * k];
        float d;
        d = bf16u_to_f(u0.x) - pm[k*4+0]; a0 += d * d;
        d = bf16u_to_f(u0.y) - pm[k*4+1]; a0 += d * d;
        d = bf16u_to_f(u0.z) - pm[k*4+2]; a0 += d * d;
        d = bf16u_to_f(u0.w) - pm[k*4+3]; a0 += d * d;
        d = bf16u_to_f(u1.x) - pm[k*4+0]; a1 += d * d;
        d = bf16u_to_f(u1.y) - pm[k*4+1]; a1 += d * d;
        d = bf16u_to_f(u1.z) - pm[k*4+2]; a1 += d * d;
        d = bf16u_to_f(u1.w) - pm[k*4+3]; a1 += d * d;
      }
      a0 = wave_reduce_sum(a0);
      a1 = wave_reduce_sum(a1);
      if (lane == 0) { wdist2[j0] = a0; wdist2[j1] = a1; }
    }
  }
  grid_bar(&sc->bar[3], TAILB);

  // ---- P4a: top3 (approx selection) + exact scalar s (block 0) ----
  if (b == 0) {
    unsigned long long b0 = ~0ULL, b1 = ~0ULL, b2 = ~0ULL;
    for (int j = t; j < N_LIB; j += 256) {
      unsigned long long pk = (((unsigned long long)__float_as_uint(wdist2[j])) << 32) | (unsigned)j;
      if (pk < b0)      { b2 = b1; b1 = b0; b0 = pk; }
      else if (pk < b1) { b2 = b1; b1 = pk; }
      else if (pk < b2) { b2 = pk; }
    }
    sm.sl[t * 3 + 0] = b0; sm.sl[t * 3 + 1] = b1; sm.sl[t * 3 + 2] = b2;
    __syncthreads();
    if (t >= 64) return;

    unsigned long long c0 = ~0ULL, c1 = ~0ULL, c2 = ~0ULL;
#pragma unroll
    for (int e = 0; e < 12; e++) {
      unsigned long long pk = sm.sl[t * 12 + e];
      if (pk < c0)      { c2 = c1; c1 = c0; c0 = pk; }
      else if (pk < c1) { c2 = c1; c1 = pk; }
      else if (pk < c2) { c2 = pk; }
    }
    unsigned long long res1 = 0, res2 = 0;
#pragma unroll
    for (int r = 0; r < 3; r++) {
      unsigned long long m = c0;
#pragma unroll
      for (int s = 1; s < 64; s <<= 1) {
        unsigned long long o = shfl_xor_u64(m, s);
        if (o < m) m = o;
      }
      if (r == 1) res1 = m;
      if (r == 2) res2 = m;
      if (c0 == m) { c0 = c1; c1 = c2; c2 = ~0ULL; }
    }
    int nA = (int)(res1 & 0xffffffffu);   // 2nd nearest
    int nB = (int)(res2 & 0xffffffffu);   // 3rd nearest

    int srow, ms2; float sstar;
    wave_pick(sc, cnt, t, &srow, &sstar, &ms2);

    float mu = meanp[0], sd = stdp[0];
    float accA = 0.f, accB = 0.f;
#pragma unroll
    for (int k = 0; k < 3; k++) {
      float4 p4 = ((const float4*)(patch + (size_t)srow * DIM))[t + 64 * k];
      float4 a4 = ((const float4*)(lib + (size_t)nA * DIM))[t + 64 * k];
      float4 b4 = ((const float4*)(lib + (size_t)nB * DIM))[t + 64 * k];
      float px = (p4.x - mu) / sd, py = (p4.y - mu) / sd;
      float pz = (p4.z - mu) / sd, pw = (p4.w - mu) / sd;
      float dax = px - a4.x, day = py - a4.y, daz = pz - a4.z, daw = pw - a4.w;
      float dbx = px - b4.x, dby = py - b4.y, dbz = pz - b4.z, dbw = pw - b4.w;
      accA += dax*dax + day*day + daz*daz + daw*daw;
      accB += dbx*dbx + dby*dby + dbz*dbz + dbw*dbw;
    }
    accA = wave_reduce_sum(accA);
    accB = wave_reduce_sum(accB);
    if (t == 0) {
      float dsq = sqrtf((float)DIM);
      float d1 = sqrtf(accA), d2v = sqrtf(accB);
      float w = 1.0f - expf(sstar / dsq) / (expf(d1 / dsq) + expf(d2v / dsq));
      out0[0] = w * sstar;
    }
    return;
  }

  // ---- P4b: fused bilinear 56->224 + 9x9 blur (blocks 1..49) ----
  if (b > 49) return;
  {
    int tile = b - 1;
    int bx = tile % 7, by = tile / 7;
    int ox0 = bx * 32, oy0 = by * 32;

    for (int i = t; i < 1600; i += 256) {
      int ly = i / 40, lx = i % 40;
      int gy = oy0 - 4 + ly; gy = gy < 0 ? 0 : (gy > 223 ? 223 : gy);
      int gx = ox0 - 4 + lx; gx = gx < 0 ? 0 : (gx > 223 ? 223 : gx);
      float sy = fminf(fmaxf(0.25f * gy - 0.375f, 0.0f), 55.0f);
      float sx = fminf(fmaxf(0.25f * gx - 0.375f, 0.0f), 55.0f);
      int y0 = (int)sy; if (y0 > 54) y0 = 54;
      int x0 = (int)sx; if (x0 > 54) x0 = 54;
      float fy = sy - y0, fx = sx - x0;
      float v00 = min_val[y0*FM + x0],     v01 = min_val[y0*FM + x0 + 1];
      float v10 = min_val[(y0+1)*FM + x0], v11 = min_val[(y0+1)*FM + x0 + 1];
      float a = v00 + fx * (v01 - v00);
      float bb = v10 + fx * (v11 - v10);
      sm.rs[i] = a + fy * (bb - a);
    }
    __syncthreads();

    float g[9]; float gs = 0.f;
#pragma unroll
    for (int i = 0; i < 9; i++) { float tt = (float)(i - 4); g[i] = expf(-(tt*tt)/32.0f); gs += g[i]; }
#pragma unroll
    for (int i = 0; i < 9; i++) g[i] /= gs;

    for (int p = t; p < 1024; p += 256) {
      int y = oy0 + p / 32, x = ox0 + (p & 31);
      float acc = 0.f;
#pragma unroll
      for (int dy = 0; dy < 9; dy++) {
        int yy = y + dy - 4;
        yy = yy < 0 ? -yy : (yy > IMGSZ - 1 ? 2*(IMGSZ-1) - yy : yy);
        int lyy = yy - (oy0 - 4);
        float ra = 0.f;
#pragma unroll
        for (int dx = 0; dx < 9; dx++) {
          int xx = x + dx - 4;
          xx = xx < 0 ? -xx : (xx > IMGSZ - 1 ? 2*(IMGSZ-1) - xx : xx);
          ra += g[dx] * sm.rs[lyy * 40 + (xx - (ox0 - 4))];
        }
        acc += g[dy] * ra;
      }
      outmap[y * IMGSZ + x] = acc;
    }
  }
}

// ================================================= host
extern "C" void kernel_launch(void* const* d_in, const int* in_sizes, int n_in,
                              void* d_out, int out_size, void* d_ws, size_t ws_size,
                              hipStream_t stream) {
  const float* patch = (const float*)d_in[0];
  const float* lib   = (const float*)d_in[1];
  const float* meanp = (const float*)d_in[2];
  const float* stdp  = (const float*)d_in[3];
  float* out = (float*)d_out;

  char* ws = (char*)d_ws;
  size_t off = 0;
  auto alloc = [&](size_t bytes) -> void* {
    void* p = ws + off;
    off = (off + bytes + 255) & ~(size_t)255;
    return p;
  };
  bf16_t* pb      = (bf16_t*)alloc((size_t)N_PATCH * DIM * sizeof(bf16_t));
  bf16_t* lb      = (bf16_t*)alloc((size_t)N_LIB * DIM * sizeof(bf16_t));
  float* a2       = (float*)alloc(N_PATCH * sizeof(float));
  float* b2       = (float*)alloc(N_LIB * sizeof(float));
  float* part     = (float*)alloc((size_t)N_PATCH_PAD * NTILES * sizeof(float));
  float* min_val  = (float*)alloc(N_PATCH * sizeof(float));
  float* wdist2   = (float*)alloc(N_LIB * sizeof(float));
  Scal*  sc       = (Scal*)alloc(sizeof(Scal));

  prep_kernel<<<N_PATCH / 4 + N_LIB / 4, 256, 0, stream>>>(patch, lib, meanp, stdp,
                                                           pb, lb, a2, b2, sc);
  gemm_min_kernel<<<GEMMB, 512, 0, stream>>>(pb, lb, a2, b2, part, sc);
  tail_kernel<<<TAILB, 256, 0, stream>>>(part, min_val, patch, lib, lb, meanp, stdp,
                                         sc, wdist2, out, out + 1);
}

// Round 4
// 333.532 us; speedup vs baseline: 1.0193x; 1.0193x over previous
//
#include <hip/hip_runtime.h>
#include <hip/hip_bf16.h>
#include <stdint.h>

// Problem constants
#define N_PATCH 3136     // 56*56 query rows
#define N_PATCH_PAD 3328 // 13 m-tiles * 256
#define N_LIB   16384    // memory bank rows
#define DIM     768
#define IMGSZ   224
#define FM      56

// GEMM tiling: 256x256 tile, BK=64, 12 K-tiles, 8-phase double-buffer schedule
#define TILE 256
#define KT2 12           // DIM/64 K-tiles
#define MT 13            // ceil(3136/256) m-tiles
#define NTILES 64        // 16384/256 n-tiles

// tail kernel: 64 blocks <= 256 CUs -> always co-resident (manual grid barrier safe)
#define TAILB 64
#define D2_MARGIN 8.0f   // ~24 sigma of bf16 d2 noise: tiles within this of best get fp32 rescan

typedef __bf16 bf16_t;
typedef __bf16 bf16x8 __attribute__((ext_vector_type(8)));
typedef __bf16 bf16x4_v __attribute__((ext_vector_type(4)));
typedef float  f32x4  __attribute__((ext_vector_type(4)));

#define FLT_MAX_ 3.402823466e+38f

// compiler fence on both sides of a hardware barrier (reads/stages must not
// cross phase boundaries; raw s_barrier alone is not a codegen memory fence)
#define BARF() do { asm volatile("" ::: "memory"); \
                    __builtin_amdgcn_s_barrier();  \
                    asm volatile("" ::: "memory"); } while (0)

struct Scal {
  unsigned long long approx_max_pack;   // (bits(sqrt-min)<<32) | (0xffffffff - row)
  unsigned long long cand_pack[64];     // per-candidate exact (bits(d2)<<32)|argmin_j
  int cand[64];
  int cand_count;
  int bar[4];                           // grid-barrier counters (one-shot each)
  int work;                             // (unused this round)
};

__device__ __forceinline__ float wave_reduce_sum(float v) {
#pragma unroll
  for (int s = 32; s > 0; s >>= 1) v += __shfl_xor(v, s, 64);
  return v;
}

__device__ __forceinline__ float wave_reduce_min(float v) {
#pragma unroll
  for (int s = 32; s > 0; s >>= 1) v = fminf(v, __shfl_xor(v, s, 64));
  return v;
}

__device__ __forceinline__ unsigned long long shfl_xor_u64(unsigned long long v, int mask) {
  unsigned lo = (unsigned)v, hi = (unsigned)(v >> 32);
  lo = __shfl_xor(lo, mask, 64);
  hi = __shfl_xor(hi, mask, 64);
  return ((unsigned long long)hi << 32) | lo;
}

// async global->LDS, 16B per lane; LDS dest = wave-uniform base + lane*size
__device__ __forceinline__ void async16(const bf16_t* g, bf16_t* l) {
  __builtin_amdgcn_global_load_lds(
      (const __attribute__((address_space(1))) unsigned int*)g,
      (__attribute__((address_space(3))) unsigned int*)l, 16, 0, 0);
}

// software grid barrier (rocPRIM pattern); REQUIRES all blocks co-resident.
__device__ __forceinline__ void grid_bar(int* ctr, int nb) {
  __syncthreads();
  if (threadIdx.x == 0) {
    __threadfence();
    atomicAdd(ctr, 1);
    while (atomicAdd(ctr, 0) < nb) __builtin_amdgcn_s_sleep(8);
    __threadfence();
  }
  __syncthreads();
}

__device__ __forceinline__ float bf16u_to_f(unsigned short u) {
  return __uint_as_float(((unsigned)u) << 16);
}

// ------------------------------------------------- prep: normalize + bf16 + norms
__global__ void prep_kernel(const float* __restrict__ patch, const float* __restrict__ lib,
                            const float* __restrict__ meanp, const float* __restrict__ stdp,
                            bf16_t* __restrict__ pb, bf16_t* __restrict__ lb,
                            float* __restrict__ a2, float* __restrict__ b2, Scal* sc) {
  int t = threadIdx.x;
  int lane = t & 63;
  if (blockIdx.x == 0) {
    if (t < 64) sc->cand_pack[t] = ~0ULL;
    if (t == 64) { sc->approx_max_pack = 0ULL; sc->cand_count = 0; }
    if (t >= 65 && t < 69) sc->bar[t - 65] = 0;
    if (t == 69) sc->work = 0;
  }
  if (blockIdx.x < N_PATCH / 4) {
    int row = blockIdx.x * 4 + (t >> 6);
    float mu = meanp[0], sd = stdp[0];
    float acc = 0.f;
#pragma unroll
    for (int k = 0; k < 3; k++) {
      float4 v = ((const float4*)(patch + (size_t)row * DIM))[lane + 64 * k];
      v.x = (v.x - mu) / sd; v.y = (v.y - mu) / sd;
      v.z = (v.z - mu) / sd; v.w = (v.w - mu) / sd;
      bf16x4_v o = {(__bf16)v.x, (__bf16)v.y, (__bf16)v.z, (__bf16)v.w};
      *(bf16x4_v*)(pb + (size_t)row * DIM + (lane + 64 * k) * 4) = o;
      acc += v.x*v.x + v.y*v.y + v.z*v.z + v.w*v.w;
    }
    acc = wave_reduce_sum(acc);
    if (lane == 0) a2[row] = acc;
  } else {
    int row = (blockIdx.x - N_PATCH / 4) * 4 + (t >> 6);
    float acc = 0.f;
#pragma unroll
    for (int k = 0; k < 3; k++) {
      float4 v = ((const float4*)(lib + (size_t)row * DIM))[lane + 64 * k];
      bf16x4_v o = {(__bf16)v.x, (__bf16)v.y, (__bf16)v.z, (__bf16)v.w};
      *(bf16x4_v*)(lb + (size_t)row * DIM + (lane + 64 * k) * 4) = o;
      acc += v.x*v.x + v.y*v.y + v.z*v.z + v.w*v.w;
    }
    acc = wave_reduce_sum(acc);
    if (lane == 0) b2[row] = acc;
  }
}

// ------------------------------------------------- fused bf16 GEMM + row-min
// m201-style 8-phase schedule, ported: 256x256 tile, BK=64, LDS
// [2 dbuf][2 half][128][64] per operand (128 KiB), 512 thr / 8 waves (2Mx4N),
// per-wave output 128x64 (acc 8x4 f32x4).
//
// Per K-tile (one half-iteration, 4 phases = C quadrants (0,0)(0,1)(1,1)(1,0)):
//   ph_a: [2 stage calls][vmcnt(2)][BAR][read B0(4)+A0(8)][16 MFMA][BAR]
//   ph_b: [read B1(4)][2 stage][BAR][16 MFMA][BAR]
//   ph_c: [read A1(8)][2 stage][BAR][16 MFMA][BAR]
//   ph_d: [2 stage][BAR][16 MFMA][BAR]
//   Operands held in registers (B0 lives all 4 phases; A overwritten at ph_c)
//   -> LDS reads = 24 KB/wave/K-tile = minimum.
// vmcnt ledger (per wave; 8 gload calls per K-tile, 2 issued per phase):
//   entering K-tile t: outstanding = 8 (tile t, issued during tile t-1's phases)
//   ph_a issues 2 (tile t+1) -> 10; vmcnt(2) retires tile t's 8; BAR makes it
//   cross-wave. Stage into buf b only after the BAR ending buf b's consumption
//   (phases of tile t-2) -> no WAR. Final K-tile uses vmcnt(0) (only drain).
//
// LDS swizzle (proven R2/R3, 0 conflicts): row r (128B line, 8x16B slots),
// slot s holds col-chunk kc = s ^ (r&7); staging applies inverse on the
// GLOBAL source address (rule #21); reads use byte = r*128 + ((kc)^(r&7))*16.
//
// Work map: static per-XCD ntile-major. XCD x owns ntiles [8x, 8x+8); its 32
// blocks sweep items i=0..103 (ntile = 8x+i/13) with stride 32 -> concurrent
// B working set ~3 tiles (1.2 MB) = L2-resident per XCD.
__global__ __launch_bounds__(512, 2)
void gemm_min_kernel(const bf16_t* __restrict__ pb, const bf16_t* __restrict__ lb,
                     const float* __restrict__ a2, const float* __restrict__ b2,
                     float* __restrict__ part) {
  __shared__ __align__(16) bf16_t As[2][2][128 * 64];   // 64 KiB
  __shared__ __align__(16) bf16_t Bs[2][2][128 * 64];   // 64 KiB

  const int t = threadIdx.x;
  const int wave = t >> 6;
  const int lane = t & 63;
  const int l15 = lane & 15;
  const int quad = lane >> 4;
  const int wm = (wave >> 2) * 128;    // 0 or 128
  const int wn = (wave & 3) * 64;      // 0,64,128,192
  const int mhw = wm >> 7;             // wave's A half index
  const int nhw = wn >> 7;             // wave's B half index
  const int wni = wn & 64;             // within-B-half row offset

  // staging dest->source maps for call q=0 (chunk t) and q=1 (chunk 512+t)
  const int L0 = t >> 3,      k0 = (t & 7) ^ (L0 & 7);
  const int L1 = 64 + (t >> 3), k1 = (t & 7) ^ (L1 & 7);
  // per-lane fragment-read swizzled slot offsets for ksub 0/1
  const int sl0 = (((0 * 4 + quad) ^ (l15 & 7)) << 4);
  const int sl1 = (((1 * 4 + quad) ^ (l15 & 7)) << 4);

  const int x = blockIdx.x & 7;        // XCD (heuristic mapping; perf-only)
  const int sblk = blockIdx.x >> 3;    // 0..31 within XCD

  for (int ii = sblk; ii < 104; ii += 32) {
    const int nt = x * 8 + ii / 13;
    const int mt = ii % 13;
    const int m0 = mt * TILE;
    const int n0 = nt * TILE;

    __syncthreads();   // fence LDS reuse (smin of previous item / new stages)

    // global source pointers: [operand-half][q]
    int rA00 = m0 + L0;        if (rA00 > N_PATCH - 1) rA00 = N_PATCH - 1;
    int rA01 = m0 + L1;        if (rA01 > N_PATCH - 1) rA01 = N_PATCH - 1;
    int rA10 = m0 + 128 + L0;  if (rA10 > N_PATCH - 1) rA10 = N_PATCH - 1;
    int rA11 = m0 + 128 + L1;  if (rA11 > N_PATCH - 1) rA11 = N_PATCH - 1;
    const bf16_t* gA00 = pb + (size_t)rA00 * DIM + k0 * 8;
    const bf16_t* gA01 = pb + (size_t)rA01 * DIM + k1 * 8;
    const bf16_t* gA10 = pb + (size_t)rA10 * DIM + k0 * 8;
    const bf16_t* gA11 = pb + (size_t)rA11 * DIM + k1 * 8;
    const bf16_t* gB00 = lb + (size_t)(n0 + L0) * DIM + k0 * 8;
    const bf16_t* gB01 = lb + (size_t)(n0 + L1) * DIM + k1 * 8;
    const bf16_t* gB10 = lb + (size_t)(n0 + 128 + L0) * DIM + k0 * 8;
    const bf16_t* gB11 = lb + (size_t)(n0 + 128 + L1) * DIM + k1 * 8;

    auto stageA = [&](int tk, int mh) {
      bf16_t* dst = &As[tk & 1][mh][0];
      const bf16_t* s0 = mh ? gA10 : gA00;
      const bf16_t* s1 = mh ? gA11 : gA01;
      async16(s0 + tk * 64, dst + t * 8);
      async16(s1 + tk * 64, dst + 4096 + t * 8);
    };
    auto stageB = [&](int tk, int nh) {
      bf16_t* dst = &Bs[tk & 1][nh][0];
      const bf16_t* s0 = nh ? gB10 : gB00;
      const bf16_t* s1 = nh ? gB11 : gB01;
      async16(s0 + tk * 64, dst + t * 8);
      async16(s1 + tk * 64, dst + 4096 + t * 8);
    };

    f32x4 acc[8][4];
#pragma unroll
    for (int mi = 0; mi < 8; mi++)
#pragma unroll
      for (int ni = 0; ni < 4; ni++) { f32x4 z = {0.f,0.f,0.f,0.f}; acc[mi][ni] = z; }

    bf16x8 afr[4][2], b0f[2][2], b1f[2][2];

    auto readA = [&](int d, int mh) {
      const char* base = (const char*)&As[d][mhw][0];
#pragma unroll
      for (int mi = 0; mi < 4; mi++) {
        int lr = mh * 64 + mi * 16 + l15;
        afr[mi][0] = *(const bf16x8*)(base + lr * 128 + sl0);
        afr[mi][1] = *(const bf16x8*)(base + lr * 128 + sl1);
      }
    };
    auto readB = [&](int d, int nh, bf16x8 (&bf)[2][2]) {
      const char* base = (const char*)&Bs[d][nhw][0];
#pragma unroll
      for (int ni = 0; ni < 2; ni++) {
        int lr = wni + nh * 32 + ni * 16 + l15;
        bf[ni][0] = *(const bf16x8*)(base + lr * 128 + sl0);
        bf[ni][1] = *(const bf16x8*)(base + lr * 128 + sl1);
      }
    };
    auto mfq = [&](int mh, int nh, bf16x8 (&bf)[2][2]) {
      __builtin_amdgcn_s_setprio(1);
#pragma unroll
      for (int mi = 0; mi < 4; mi++)
#pragma unroll
        for (int ni = 0; ni < 2; ni++) {
          acc[mh*4+mi][nh*2+ni] = __builtin_amdgcn_mfma_f32_16x16x32_bf16(
              afr[mi][0], bf[ni][0], acc[mh*4+mi][nh*2+ni], 0, 0, 0);
          acc[mh*4+mi][nh*2+ni] = __builtin_amdgcn_mfma_f32_16x16x32_bf16(
              afr[mi][1], bf[ni][1], acc[mh*4+mi][nh*2+ni], 0, 0, 0);
        }
      __builtin_amdgcn_s_setprio(0);
    };

    // one K-tile: 4 phases; d = its buffer (compile-time at call sites),
    // tst = K-tile to stage (goes to buf tst&1 == !d), stg = stage enable
    auto half_iter = [&](int d, int tst, bool stg) {
      // ---- ph_a: verify buf d, compute quadrant (0,0)
      if (stg) {
        stageA(tst, 0);
        asm volatile("s_waitcnt vmcnt(2)" ::: "memory");
      } else {
        asm volatile("s_waitcnt vmcnt(0)" ::: "memory");
      }
      BARF();
      readB(d, 0, b0f);
      readA(d, 0);
      mfq(0, 0, b0f);
      BARF();
      // ---- ph_b: read B(nh1), stage, quadrant (0,1)
      readB(d, 1, b1f);
      if (stg) stageA(tst, 1);
      BARF();
      mfq(0, 1, b1f);
      BARF();
      // ---- ph_c: read A(mh1) (overwrites afr), stage, quadrant (1,1)
      readA(d, 1);
      if (stg) stageB(tst, 0);
      BARF();
      mfq(1, 1, b1f);
      BARF();
      // ---- ph_d: stage, quadrant (1,0)  (afr=A1, b0f held from ph_a)
      if (stg) stageB(tst, 1);
      BARF();
      mfq(1, 0, b0f);
      BARF();
    };

    // prologue: stage K-tile 0 (8 calls) -> buf0
    stageA(0, 0); stageA(0, 1); stageB(0, 0); stageB(0, 1);

    for (int tt = 0; tt < 10; tt += 2) {
      half_iter(0, tt + 1, true);      // compute tile tt   (buf0), stage tt+1
      half_iter(1, tt + 2, true);      // compute tile tt+1 (buf1), stage tt+2
    }
    half_iter(0, 11, true);            // compute tile 10, stage tile 11
    half_iter(1, 12, false);           // compute tile 11, drain (vmcnt 0)

    // ---- epilogue: d2 = a2 + b2 - 2ab, row-min, cross-wave via smin ----
    __syncthreads();
    unsigned* smin = (unsigned*)&As[0][0][0];
    if (t < 256) smin[t] = 0xffffffffu;
    __syncthreads();

    float b2n[4];
#pragma unroll
    for (int ni = 0; ni < 4; ni++) b2n[ni] = b2[n0 + wn + ni * 16 + l15];

#pragma unroll
    for (int mi = 0; mi < 8; mi++) {
#pragma unroll
      for (int r = 0; r < 4; r++) {
        int rloc = wm + mi * 16 + quad * 4 + r;
        int mrow = m0 + rloc;
        float a2v = a2[mrow < N_PATCH ? mrow : (N_PATCH - 1)];
        // C/D layout: col = lane&15, row = quad*4 + reg  [m89/m91]
        float best = a2v + b2n[0] - 2.0f * acc[mi][0][r];
#pragma unroll
        for (int ni = 1; ni < 4; ni++)
          best = fminf(best, a2v + b2n[ni] - 2.0f * acc[mi][ni][r]);
        best = fmaxf(best, 0.0f);
#pragma unroll
        for (int s = 1; s < 16; s <<= 1)
          best = fminf(best, __shfl_xor(best, s, 64));
        if (l15 == 0) atomicMin(&smin[rloc], __float_as_uint(best));
      }
    }
    __syncthreads();
    if (t < 256) part[(size_t)nt * N_PATCH_PAD + m0 + t] = __uint_as_float(smin[t]);
  }
}

// inline "pick": wave-level max over candidates
__device__ __forceinline__ void wave_pick(const Scal* sc, int cnt, int lane,
                                          int* srow, float* sstar, int* ms) {
  unsigned long long pk = 0ULL;
  int rowv = 0, msv = 0;
  if (lane < cnt) {
    unsigned long long cp = sc->cand_pack[lane];
    rowv = sc->cand[lane];
    msv = (int)(cp & 0xffffffffu);
    pk = (cp & 0xffffffff00000000ULL) | (unsigned)(0xffffffffu - (unsigned)rowv);
  }
  unsigned long long m = pk;
#pragma unroll
  for (int s = 1; s < 64; s <<= 1) {
    unsigned long long o = shfl_xor_u64(m, s);
    if (o > m) m = o;
  }
  unsigned long long mask = __ballot(pk == m && lane < cnt);
  int wl = (int)(__ffsll((long long)mask) - 1);
  *srow = __shfl(rowv, wl, 64);
  *ms   = __shfl(msv, wl, 64);
  *sstar = sqrtf(__uint_as_float((unsigned)(m >> 32)));
}

// ------------------------------------------------- tail (single dispatch, 64 blocks):
// P0 finalize -> bar -> P1 collect -> bar -> P2 tile-targeted fp32 refine -> bar ->
// P3 wdist (bf16, selection only) -> bar -> P4 (top3+s on block 0 || resize+blur 1..49)
__global__ __launch_bounds__(256, 2)
void tail_kernel(const float* __restrict__ part, float* __restrict__ min_val,
                 const float* __restrict__ patch, const float* __restrict__ lib,
                 const bf16_t* __restrict__ lb,
                 const float* __restrict__ meanp, const float* __restrict__ stdp,
                 Scal* __restrict__ sc, float* __restrict__ wdist2,
                 float* __restrict__ out0, float* __restrict__ outmap) {
  __shared__ union {
    unsigned long long sl[768];   // top3
    float rs[40 * 40];            // resize halo
  } sm;
  __shared__ float redbuf[4];
  __shared__ int s_cnt;

  const int t = threadIdx.x;
  const int b = blockIdx.x;
  const int wave = t >> 6, lane = t & 63;

  // ---- P0: finalize (blocks 0..12 cover 3136 rows; coalesced column reads) ----
  {
    int row = b * 256 + t;
    if (row < N_PATCH) {
      float m = FLT_MAX_;
#pragma unroll 8
      for (int nt = 0; nt < NTILES; nt++)
        m = fminf(m, part[(size_t)nt * N_PATCH_PAD + row]);
      float v = sqrtf(m);
      min_val[row] = v;
      unsigned long long mp = (((unsigned long long)__float_as_uint(v)) << 32) |
                              (unsigned)(0xffffffffu - (unsigned)row);  // ties -> smaller row
      atomicMax(&sc->approx_max_pack, mp);
    }
  }
  grid_bar(&sc->bar[0], TAILB);

  // ---- P1: collect candidates (block 0; margin 0.05 ~ 10 sigma of bf16 dist noise) ----
  if (b == 0) {
    float amax = __uint_as_float((unsigned)(atomicMax(&sc->approx_max_pack, 0ULL) >> 32));
    for (int i = t; i < N_PATCH; i += 256) {
      if (min_val[i] >= amax - 0.05f) {
        int p = atomicAdd(&sc->cand_count, 1);
        if (p < 64) sc->cand[p] = i;
      }
    }
  }
  grid_bar(&sc->bar[1], TAILB);

  if (t == 0) s_cnt = atomicAdd(&sc->cand_count, 0);
  __syncthreads();
  int cnt = s_cnt; if (cnt > 64) cnt = 64;

  // ---- P2: tile-targeted exact refine. Block b owns ntile b (256 lib rows).
  {
    float mu = meanp[0], sd = stdp[0];
    for (int c = 0; c < cnt; c++) {
      int row = sc->cand[c];
      float pv_ = (t < NTILES) ? part[(size_t)t * N_PATCH_PAD + row] : FLT_MAX_;
      pv_ = wave_reduce_min(pv_);
      if (lane == 0) redbuf[wave] = pv_;
      __syncthreads();
      float bmin = fminf(fminf(redbuf[0], redbuf[1]), fminf(redbuf[2], redbuf[3]));
      __syncthreads();

      float4 pv[3];
#pragma unroll
      for (int k = 0; k < 3; k++) {
        float4 v = ((const float4*)(patch + (size_t)row * DIM))[lane + 64 * k];
        v.x = (v.x - mu) / sd; v.y = (v.y - mu) / sd;
        v.z = (v.z - mu) / sd; v.w = (v.w - mu) / sd;
        pv[k] = v;
      }
      int nt = b;
      float pmin = part[(size_t)nt * N_PATCH_PAD + row];   // uniform -> broadcast
      if (pmin <= bmin + D2_MARGIN) {
        unsigned long long best = ~0ULL;
        int jb = nt * 256 + wave * 64;
        for (int rr = 0; rr < 64; rr++) {
          int j = jb + rr;
          const float4* pl = (const float4*)(lib + (size_t)j * DIM);
          float acc = 0.f;
#pragma unroll
          for (int k = 0; k < 3; k++) {
            float4 l = pl[lane + 64 * k];
            float dx = pv[k].x - l.x, dy = pv[k].y - l.y;
            float dz = pv[k].z - l.z, dw = pv[k].w - l.w;
            acc += dx*dx + dy*dy + dz*dz + dw*dw;
          }
          acc = wave_reduce_sum(acc);
          unsigned long long pk = (((unsigned long long)__float_as_uint(acc)) << 32) | (unsigned)j;
          if (pk < best) best = pk;
        }
        if (lane == 0) atomicMin(&sc->cand_pack[c], best);
      }
    }
  }
  grid_bar(&sc->bar[2], TAILB);

  // ---- P3: wdist on bf16 lb (selection only; exact d's recomputed in P4a) ----
  {
    int srow_, ms; float ss_;
    wave_pick(sc, cnt, lane, &srow_, &ss_, &ms);
    float pm[12];
    const ushort4* pms = (const ushort4*)(lb + (size_t)ms * DIM);
#pragma unroll
    for (int k = 0; k < 3; k++) {
      ushort4 u = pms[lane + 64 * k];
      pm[k*4+0] = bf16u_to_f(u.x); pm[k*4+1] = bf16u_to_f(u.y);
      pm[k*4+2] = bf16u_to_f(u.z); pm[k*4+3] = bf16u_to_f(u.w);
    }
    int jbase = b * 256 + wave * 64;
    for (int rr = 0; rr < 64; rr += 2) {
      int j0 = jbase + rr, j1 = j0 + 1;
      const ushort4* r0 = (const ushort4*)(lb + (size_t)j0 * DIM);
      const ushort4* r1 = (const ushort4*)(lb + (size_t)j1 * DIM);
      float a0 = 0.f, a1 = 0.f;
#pragma unroll
      for (int k = 0; k < 3; k++) {
        ushort4 u0 = r0[lane + 64 * k];
        ushort4 u1 = r1[lane + 64 * k];
        float d;
        d = bf16u_to_f(u0.x) - pm[k*4+0]; a0 += d * d;
        d = bf16u_to_f(u0.y) - pm[k*4+1]; a0 += d * d;
        d = bf16u_to_f(u0.z) - pm[k*4+2]; a0 += d * d;
        d = bf16u_to_f(u0.w) - pm[k*4+3]; a0 += d * d;
        d = bf16u_to_f(u1.x) - pm[k*4+0]; a1 += d * d;
        d = bf16u_to_f(u1.y) - pm[k*4+1]; a1 += d * d;
        d = bf16u_to_f(u1.z) - pm[k*4+2]; a1 += d * d;
        d = bf16u_to_f(u1.w) - pm[k*4+3]; a1 += d * d;
      }
      a0 = wave_reduce_sum(a0);
      a1 = wave_reduce_sum(a1);
      if (lane == 0) { wdist2[j0] = a0; wdist2[j1] = a1; }
    }
  }
  grid_bar(&sc->bar[3], TAILB);

  // ---- P4a: top3 (approx selection) + exact scalar s (block 0) ----
  if (b == 0) {
    unsigned long long b0 = ~0ULL, b1 = ~0ULL, b2 = ~0ULL;
    for (int j = t; j < N_LIB; j += 256) {
      unsigned long long pk = (((unsigned long long)__float_as_uint(wdist2[j])) << 32) | (unsigned)j;
      if (pk < b0)      { b2 = b1; b1 = b0; b0 = pk; }
      else if (pk < b1) { b2 = b1; b1 = pk; }
      else if (pk < b2) { b2 = pk; }
    }
    sm.sl[t * 3 + 0] = b0; sm.sl[t * 3 + 1] = b1; sm.sl[t * 3 + 2] = b2;
    __syncthreads();
    if (t >= 64) return;

    unsigned long long c0 = ~0ULL, c1 = ~0ULL, c2 = ~0ULL;
#pragma unroll
    for (int e = 0; e < 12; e++) {
      unsigned long long pk = sm.sl[t * 12 + e];
      if (pk < c0)      { c2 = c1; c1 = c0; c0 = pk; }
      else if (pk < c1) { c2 = c1; c1 = pk; }
      else if (pk < c2) { c2 = pk; }
    }
    unsigned long long res1 = 0, res2 = 0;
#pragma unroll
    for (int r = 0; r < 3; r++) {
      unsigned long long m = c0;
#pragma unroll
      for (int s = 1; s < 64; s <<= 1) {
        unsigned long long o = shfl_xor_u64(m, s);
        if (o < m) m = o;
      }
      if (r == 1) res1 = m;
      if (r == 2) res2 = m;
      if (c0 == m) { c0 = c1; c1 = c2; c2 = ~0ULL; }
    }
    int nA = (int)(res1 & 0xffffffffu);   // 2nd nearest
    int nB = (int)(res2 & 0xffffffffu);   // 3rd nearest

    int srow, ms2; float sstar;
    wave_pick(sc, cnt, t, &srow, &sstar, &ms2);

    float mu = meanp[0], sd = stdp[0];
    float accA = 0.f, accB = 0.f;
#pragma unroll
    for (int k = 0; k < 3; k++) {
      float4 p4 = ((const float4*)(patch + (size_t)srow * DIM))[t + 64 * k];
      float4 a4 = ((const float4*)(lib + (size_t)nA * DIM))[t + 64 * k];
      float4 b4 = ((const float4*)(lib + (size_t)nB * DIM))[t + 64 * k];
      float px = (p4.x - mu) / sd, py = (p4.y - mu) / sd;
      float pz = (p4.z - mu) / sd, pw = (p4.w - mu) / sd;
      float dax = px - a4.x, day = py - a4.y, daz = pz - a4.z, daw = pw - a4.w;
      float dbx = px - b4.x, dby = py - b4.y, dbz = pz - b4.z, dbw = pw - b4.w;
      accA += dax*dax + day*day + daz*daz + daw*daw;
      accB += dbx*dbx + dby*dby + dbz*dbz + dbw*dbw;
    }
    accA = wave_reduce_sum(accA);
    accB = wave_reduce_sum(accB);
    if (t == 0) {
      float dsq = sqrtf((float)DIM);
      float d1 = sqrtf(accA), d2v = sqrtf(accB);
      float w = 1.0f - expf(sstar / dsq) / (expf(d1 / dsq) + expf(d2v / dsq));
      out0[0] = w * sstar;
    }
    return;
  }

  // ---- P4b: fused bilinear 56->224 + 9x9 blur (blocks 1..49) ----
  if (b > 49) return;
  {
    int tile = b - 1;
    int bx = tile % 7, by = tile / 7;
    int ox0 = bx * 32, oy0 = by * 32;

    for (int i = t; i < 1600; i += 256) {
      int ly = i / 40, lx = i % 40;
      int gy = oy0 - 4 + ly; gy = gy < 0 ? 0 : (gy > 223 ? 223 : gy);
      int gx = ox0 - 4 + lx; gx = gx < 0 ? 0 : (gx > 223 ? 223 : gx);
      float sy = fminf(fmaxf(0.25f * gy - 0.375f, 0.0f), 55.0f);
      float sx = fminf(fmaxf(0.25f * gx - 0.375f, 0.0f), 55.0f);
      int y0 = (int)sy; if (y0 > 54) y0 = 54;
      int x0 = (int)sx; if (x0 > 54) x0 = 54;
      float fy = sy - y0, fx = sx - x0;
      float v00 = min_val[y0*FM + x0],     v01 = min_val[y0*FM + x0 + 1];
      float v10 = min_val[(y0+1)*FM + x0], v11 = min_val[(y0+1)*FM + x0 + 1];
      float a = v00 + fx * (v01 - v00);
      float bb = v10 + fx * (v11 - v10);
      sm.rs[i] = a + fy * (bb - a);
    }
    __syncthreads();

    float g[9]; float gs = 0.f;
#pragma unroll
    for (int i = 0; i < 9; i++) { float tt = (float)(i - 4); g[i] = expf(-(tt*tt)/32.0f); gs += g[i]; }
#pragma unroll
    for (int i = 0; i < 9; i++) g[i] /= gs;

    for (int p = t; p < 1024; p += 256) {
      int y = oy0 + p / 32, x = ox0 + (p & 31);
      float acc = 0.f;
#pragma unroll
      for (int dy = 0; dy < 9; dy++) {
        int yy = y + dy - 4;
        yy = yy < 0 ? -yy : (yy > IMGSZ - 1 ? 2*(IMGSZ-1) - yy : yy);
        int lyy = yy - (oy0 - 4);
        float ra = 0.f;
#pragma unroll
        for (int dx = 0; dx < 9; dx++) {
          int xx = x + dx - 4;
          xx = xx < 0 ? -xx : (xx > IMGSZ - 1 ? 2*(IMGSZ-1) - xx : xx);
          ra += g[dx] * sm.rs[lyy * 40 + (xx - (ox0 - 4))];
        }
        acc += g[dy] * ra;
      }
      outmap[y * IMGSZ + x] = acc;
    }
  }
}

// ================================================= host
extern "C" void kernel_launch(void* const* d_in, const int* in_sizes, int n_in,
                              void* d_out, int out_size, void* d_ws, size_t ws_size,
                              hipStream_t stream) {
  const float* patch = (const float*)d_in[0];
  const float* lib   = (const float*)d_in[1];
  const float* meanp = (const float*)d_in[2];
  const float* stdp  = (const float*)d_in[3];
  float* out = (float*)d_out;

  char* ws = (char*)d_ws;
  size_t off = 0;
  auto alloc = [&](size_t bytes) -> void* {
    void* p = ws + off;
    off = (off + bytes + 255) & ~(size_t)255;
    return p;
  };
  bf16_t* pb      = (bf16_t*)alloc((size_t)N_PATCH * DIM * sizeof(bf16_t));
  bf16_t* lb      = (bf16_t*)alloc((size_t)N_LIB * DIM * sizeof(bf16_t));
  float* a2       = (float*)alloc(N_PATCH * sizeof(float));
  float* b2       = (float*)alloc(N_LIB * sizeof(float));
  float* part     = (float*)alloc((size_t)N_PATCH_PAD * NTILES * sizeof(float));
  float* min_val  = (float*)alloc(N_PATCH * sizeof(float));
  float* wdist2   = (float*)alloc(N_LIB * sizeof(float));
  Scal*  sc       = (Scal*)alloc(sizeof(Scal));

  prep_kernel<<<N_PATCH / 4 + N_LIB / 4, 256, 0, stream>>>(patch, lib, meanp, stdp,
                                                           pb, lb, a2, b2, sc);
  gemm_min_kernel<<<256, 512, 0, stream>>>(pb, lb, a2, b2, part);
  tail_kernel<<<TAILB, 256, 0, stream>>>(part, min_val, patch, lib, lb, meanp, stdp,
                                         sc, wdist2, out, out + 1);
}

// Round 5
// 324.486 us; speedup vs baseline: 1.0477x; 1.0279x over previous
//
#include <hip/hip_runtime.h>
#include <hip/hip_bf16.h>
#include <stdint.h>

// Problem constants
#define N_PATCH 3136     // 56*56 query rows
#define N_PATCH_PAD 3328 // 13 m-tiles * 256 (pb padded to this, pad rows zeroed)
#define N_LIB   16384    // memory bank rows
#define DIM     768
#define IMGSZ   224
#define FM      56

// GEMM tiling: 256x256 tile, BK=64, 12 K-tiles, 8-phase double-buffer schedule
#define TILE 256
#define KT2 12           // DIM/64 K-tiles
#define MT 13            // m-tiles
#define NTILES 64        // 16384/256 n-tiles

// tail kernel: 64 blocks <= 256 CUs -> always co-resident (manual grid barrier safe)
#define TAILB 64
#define D2_MARGIN 8.0f   // ~24 sigma of bf16 d2 noise: tiles within this of best get fp32 rescan

typedef __bf16 bf16_t;
typedef __bf16 bf16x8 __attribute__((ext_vector_type(8)));
typedef __bf16 bf16x4_v __attribute__((ext_vector_type(4)));
typedef float  f32x4  __attribute__((ext_vector_type(4)));

#define FLT_MAX_ 3.402823466e+38f

// compiler fence on both sides of a hardware barrier
#define BARF() do { asm volatile("" ::: "memory"); \
                    __builtin_amdgcn_s_barrier();  \
                    asm volatile("" ::: "memory"); } while (0)

struct Scal {
  unsigned long long approx_max_pack;   // (bits(sqrt-min)<<32) | (0xffffffff - row)
  unsigned long long cand_pack[64];     // per-candidate exact (bits(d2)<<32)|argmin_j
  int cand[64];
  int cand_count;
  int bar[4];                           // grid-barrier counters (one-shot each)
  int work;                             // (unused this round)
};

__device__ __forceinline__ float wave_reduce_sum(float v) {
#pragma unroll
  for (int s = 32; s > 0; s >>= 1) v += __shfl_xor(v, s, 64);
  return v;
}

__device__ __forceinline__ float wave_reduce_min(float v) {
#pragma unroll
  for (int s = 32; s > 0; s >>= 1) v = fminf(v, __shfl_xor(v, s, 64));
  return v;
}

__device__ __forceinline__ unsigned long long shfl_xor_u64(unsigned long long v, int mask) {
  unsigned lo = (unsigned)v, hi = (unsigned)(v >> 32);
  lo = __shfl_xor(lo, mask, 64);
  hi = __shfl_xor(hi, mask, 64);
  return ((unsigned long long)hi << 32) | lo;
}

// async global->LDS, 16B per lane; LDS dest = wave-uniform base + lane*size
__device__ __forceinline__ void async16(const bf16_t* g, bf16_t* l) {
  __builtin_amdgcn_global_load_lds(
      (const __attribute__((address_space(1))) unsigned int*)g,
      (__attribute__((address_space(3))) unsigned int*)l, 16, 0, 0);
}

// software grid barrier (rocPRIM pattern); REQUIRES all blocks co-resident.
__device__ __forceinline__ void grid_bar(int* ctr, int nb) {
  __syncthreads();
  if (threadIdx.x == 0) {
    __threadfence();
    atomicAdd(ctr, 1);
    while (atomicAdd(ctr, 0) < nb) __builtin_amdgcn_s_sleep(8);
    __threadfence();
  }
  __syncthreads();
}

__device__ __forceinline__ float bf16u_to_f(unsigned short u) {
  return __uint_as_float(((unsigned)u) << 16);
}

// ------------------------------------------------- prep: normalize + bf16 + norms
// blocks [0, 832): patch rows (3136 real + 192 zero-pad); rest: lib rows
__global__ void prep_kernel(const float* __restrict__ patch, const float* __restrict__ lib,
                            const float* __restrict__ meanp, const float* __restrict__ stdp,
                            bf16_t* __restrict__ pb, bf16_t* __restrict__ lb,
                            float* __restrict__ a2, float* __restrict__ b2, Scal* sc) {
  int t = threadIdx.x;
  int lane = t & 63;
  if (blockIdx.x == 0) {
    if (t < 64) sc->cand_pack[t] = ~0ULL;
    if (t == 64) { sc->approx_max_pack = 0ULL; sc->cand_count = 0; }
    if (t >= 65 && t < 69) sc->bar[t - 65] = 0;
    if (t == 69) sc->work = 0;
  }
  if (blockIdx.x < N_PATCH_PAD / 4) {
    int row = blockIdx.x * 4 + (t >> 6);
    if (row < N_PATCH) {
      float mu = meanp[0], sd = stdp[0];
      float acc = 0.f;
#pragma unroll
      for (int k = 0; k < 3; k++) {
        float4 v = ((const float4*)(patch + (size_t)row * DIM))[lane + 64 * k];
        v.x = (v.x - mu) / sd; v.y = (v.y - mu) / sd;
        v.z = (v.z - mu) / sd; v.w = (v.w - mu) / sd;
        bf16x4_v o = {(__bf16)v.x, (__bf16)v.y, (__bf16)v.z, (__bf16)v.w};
        *(bf16x4_v*)(pb + (size_t)row * DIM + (lane + 64 * k) * 4) = o;
        acc += v.x*v.x + v.y*v.y + v.z*v.z + v.w*v.w;
      }
      acc = wave_reduce_sum(acc);
      if (lane == 0) a2[row] = acc;
    } else {
      bf16x4_v z = {(__bf16)0.f, (__bf16)0.f, (__bf16)0.f, (__bf16)0.f};
#pragma unroll
      for (int k = 0; k < 3; k++)
        *(bf16x4_v*)(pb + (size_t)row * DIM + (lane + 64 * k) * 4) = z;
    }
  } else {
    int row = (blockIdx.x - N_PATCH_PAD / 4) * 4 + (t >> 6);
    float acc = 0.f;
#pragma unroll
    for (int k = 0; k < 3; k++) {
      float4 v = ((const float4*)(lib + (size_t)row * DIM))[lane + 64 * k];
      bf16x4_v o = {(__bf16)v.x, (__bf16)v.y, (__bf16)v.z, (__bf16)v.w};
      *(bf16x4_v*)(lb + (size_t)row * DIM + (lane + 64 * k) * 4) = o;
      acc += v.x*v.x + v.y*v.y + v.z*v.z + v.w*v.w;
    }
    acc = wave_reduce_sum(acc);
    if (lane == 0) b2[row] = acc;
  }
}

// ------------------------------------------------- fused bf16 GEMM + row-min
// R4 (m201-style 8-phase) schedule, spill-fixed:
//  - pb padded to 3328 rows -> no A row clamps, 1 base pointer per operand
//    (row-block offsets are uniform compile-time constants; swizzle map is
//    offset-invariant since 64 % 8 == 0 -> k-chunk map identical per block)
//  - B fragments NOT held across the K-tile: ph_d re-reads B0 (4 KB/wave,
//    conflict-free) -> live frags = afr(32) + bf(16) = 48 VGPR
//  Target: acc 128 + frags 48 + ptrs/misc ~35 < 256-reg cap -> no scratch.
//
// Schedule per K-tile (buf d, stage tile tst into buf !d):
//  ph_a: [stageA(tst,0)][vmcnt(2)][BAR][read B0,A0][16 MFMA][BAR]
//  ph_b: [read B1][stageA(tst,1)][BAR][16 MFMA][BAR]
//  ph_c: [read A1][stageB(tst,0)][BAR][16 MFMA][BAR]
//  ph_d: [read B0][stageB(tst,1)][BAR][16 MFMA][BAR]
// vmcnt ledger: entering ph_a outstanding = 8 (tile t) +2 (just issued) = 10;
// vmcnt(2) retires exactly tile t's 8 (FIFO). Stage into buf !d is WAR-safe:
// buf !d's last reads (tile t-1) completed before tile t's ph_a barrier.
// LDS swizzle (0 conflicts, proven R2-R4): line r = 8x16B slots, slot s holds
// k-chunk s^(r&7); inverse applied on global source address (rule #21).
__global__ __launch_bounds__(512, 2)
void gemm_min_kernel(const bf16_t* __restrict__ pb, const bf16_t* __restrict__ lb,
                     const float* __restrict__ a2, const float* __restrict__ b2,
                     float* __restrict__ part) {
  __shared__ __align__(16) bf16_t As[2][2][128 * 64];   // 64 KiB
  __shared__ __align__(16) bf16_t Bs[2][2][128 * 64];   // 64 KiB

  const int t = threadIdx.x;
  const int wave = t >> 6;
  const int lane = t & 63;
  const int l15 = lane & 15;
  const int quad = lane >> 4;
  const int wm = (wave >> 2) * 128;    // 0 or 128
  const int wn = (wave & 3) * 64;      // 0,64,128,192
  const int mhw = wm >> 7;             // wave's A half index
  const int nhw = wn >> 7;             // wave's B half index
  const int wni = wn & 64;             // within-B-half row offset

  // staging dest->source map (identical for both 64-line sub-blocks since
  // the +64 line offset doesn't change line&7): dest line L = t>>3 within
  // sub-block, slot s = t&7 holds k-chunk k0 = s ^ (L&7)
  const int L0 = t >> 3;
  const int k0 = (t & 7) ^ (L0 & 7);
  // per-lane fragment-read swizzled slot offsets for ksub 0/1
  const int sl0 = (((0 * 4 + quad) ^ (l15 & 7)) << 4);
  const int sl1 = (((1 * 4 + quad) ^ (l15 & 7)) << 4);

  const int x = blockIdx.x & 7;        // XCD (heuristic mapping; perf-only)
  const int sblk = blockIdx.x >> 3;    // 0..31 within XCD

  for (int ii = sblk; ii < 104; ii += 32) {
    const int nt = x * 8 + ii / 13;
    const int mt = ii % 13;
    const int m0 = mt * TILE;
    const int n0 = nt * TILE;

    __syncthreads();   // fence LDS reuse (smin of previous item / new stages)

    // single base pointer per operand; row-block offsets are uniform constants
    const bf16_t* gA = pb + (size_t)(m0 + L0) * DIM + k0 * 8;
    const bf16_t* gB = lb + (size_t)(n0 + L0) * DIM + k0 * 8;

    auto stageA = [&](int tk, int mh) {
      bf16_t* dst = &As[tk & 1][mh][0];
      const bf16_t* s = gA + (size_t)(mh * 128) * DIM + tk * 64;
      async16(s, dst + t * 8);
      async16(s + (size_t)64 * DIM, dst + 4096 + t * 8);
    };
    auto stageB = [&](int tk, int nh) {
      bf16_t* dst = &Bs[tk & 1][nh][0];
      const bf16_t* s = gB + (size_t)(nh * 128) * DIM + tk * 64;
      async16(s, dst + t * 8);
      async16(s + (size_t)64 * DIM, dst + 4096 + t * 8);
    };

    f32x4 acc[8][4];
#pragma unroll
    for (int mi = 0; mi < 8; mi++)
#pragma unroll
      for (int ni = 0; ni < 4; ni++) { f32x4 z = {0.f,0.f,0.f,0.f}; acc[mi][ni] = z; }

    bf16x8 afr[4][2], bf[2][2];

    auto readA = [&](int d, int mh) {
      const char* base = (const char*)&As[d][mhw][0];
#pragma unroll
      for (int mi = 0; mi < 4; mi++) {
        int lr = mh * 64 + mi * 16 + l15;
        afr[mi][0] = *(const bf16x8*)(base + lr * 128 + sl0);
        afr[mi][1] = *(const bf16x8*)(base + lr * 128 + sl1);
      }
    };
    auto readB = [&](int d, int nh) {
      const char* base = (const char*)&Bs[d][nhw][0];
#pragma unroll
      for (int ni = 0; ni < 2; ni++) {
        int lr = wni + nh * 32 + ni * 16 + l15;
        bf[ni][0] = *(const bf16x8*)(base + lr * 128 + sl0);
        bf[ni][1] = *(const bf16x8*)(base + lr * 128 + sl1);
      }
    };
    auto mfq = [&](int mh, int nh) {
      __builtin_amdgcn_s_setprio(1);
#pragma unroll
      for (int mi = 0; mi < 4; mi++)
#pragma unroll
        for (int ni = 0; ni < 2; ni++) {
          acc[mh*4+mi][nh*2+ni] = __builtin_amdgcn_mfma_f32_16x16x32_bf16(
              afr[mi][0], bf[ni][0], acc[mh*4+mi][nh*2+ni], 0, 0, 0);
          acc[mh*4+mi][nh*2+ni] = __builtin_amdgcn_mfma_f32_16x16x32_bf16(
              afr[mi][1], bf[ni][1], acc[mh*4+mi][nh*2+ni], 0, 0, 0);
        }
      __builtin_amdgcn_s_setprio(0);
    };

    auto half_iter = [&](int d, int tst, bool stg) {
      // ---- ph_a: prove buf d, compute quadrant (0,0)
      if (stg) {
        stageA(tst, 0);
        asm volatile("s_waitcnt vmcnt(2)" ::: "memory");
      } else {
        asm volatile("s_waitcnt vmcnt(0)" ::: "memory");
      }
      BARF();
      readB(d, 0);
      readA(d, 0);
      mfq(0, 0);
      BARF();
      // ---- ph_b: quadrant (0,1)
      readB(d, 1);
      if (stg) stageA(tst, 1);
      BARF();
      mfq(0, 1);
      BARF();
      // ---- ph_c: quadrant (1,1)  (bf = B1 still live)
      readA(d, 1);
      if (stg) stageB(tst, 0);
      BARF();
      mfq(1, 1);
      BARF();
      // ---- ph_d: quadrant (1,0)  (re-read B0)
      readB(d, 0);
      if (stg) stageB(tst, 1);
      BARF();
      mfq(1, 0);
      BARF();
    };

    // prologue: stage K-tile 0 (8 calls) -> buf0
    stageA(0, 0); stageA(0, 1); stageB(0, 0); stageB(0, 1);

    for (int tt = 0; tt < 10; tt += 2) {
      half_iter(0, tt + 1, true);      // compute tile tt   (buf0), stage tt+1
      half_iter(1, tt + 2, true);      // compute tile tt+1 (buf1), stage tt+2
    }
    half_iter(0, 11, true);            // compute tile 10, stage tile 11
    half_iter(1, 12, false);           // compute tile 11, drain (vmcnt 0)

    // ---- epilogue: d2 = a2 + b2 - 2ab, row-min, cross-wave via smin ----
    __syncthreads();
    unsigned* smin = (unsigned*)&As[0][0][0];
    if (t < 256) smin[t] = 0xffffffffu;
    __syncthreads();

    float b2n[4];
#pragma unroll
    for (int ni = 0; ni < 4; ni++) b2n[ni] = b2[n0 + wn + ni * 16 + l15];

#pragma unroll
    for (int mi = 0; mi < 8; mi++) {
#pragma unroll
      for (int r = 0; r < 4; r++) {
        int rloc = wm + mi * 16 + quad * 4 + r;
        int mrow = m0 + rloc;
        float a2v = a2[mrow < N_PATCH ? mrow : (N_PATCH - 1)];
        // C/D layout: col = lane&15, row = quad*4 + reg  [m89/m91]
        float best = a2v + b2n[0] - 2.0f * acc[mi][0][r];
#pragma unroll
        for (int ni = 1; ni < 4; ni++)
          best = fminf(best, a2v + b2n[ni] - 2.0f * acc[mi][ni][r]);
        best = fmaxf(best, 0.0f);
#pragma unroll
        for (int s = 1; s < 16; s <<= 1)
          best = fminf(best, __shfl_xor(best, s, 64));
        if (l15 == 0) atomicMin(&smin[rloc], __float_as_uint(best));
      }
    }
    __syncthreads();
    if (t < 256) part[(size_t)nt * N_PATCH_PAD + m0 + t] = __uint_as_float(smin[t]);
  }
}

// inline "pick": wave-level max over candidates
__device__ __forceinline__ void wave_pick(const Scal* sc, int cnt, int lane,
                                          int* srow, float* sstar, int* ms) {
  unsigned long long pk = 0ULL;
  int rowv = 0, msv = 0;
  if (lane < cnt) {
    unsigned long long cp = sc->cand_pack[lane];
    rowv = sc->cand[lane];
    msv = (int)(cp & 0xffffffffu);
    pk = (cp & 0xffffffff00000000ULL) | (unsigned)(0xffffffffu - (unsigned)rowv);
  }
  unsigned long long m = pk;
#pragma unroll
  for (int s = 1; s < 64; s <<= 1) {
    unsigned long long o = shfl_xor_u64(m, s);
    if (o > m) m = o;
  }
  unsigned long long mask = __ballot(pk == m && lane < cnt);
  int wl = (int)(__ffsll((long long)mask) - 1);
  *srow = __shfl(rowv, wl, 64);
  *ms   = __shfl(msv, wl, 64);
  *sstar = sqrtf(__uint_as_float((unsigned)(m >> 32)));
}

// ------------------------------------------------- tail (single dispatch, 64 blocks):
// P0 finalize -> bar -> P1 collect -> bar -> P2 tile-targeted fp32 refine -> bar ->
// P3 wdist (bf16, selection only) -> bar -> P4 (top3+s on block 0 || resize+blur 1..49)
__global__ __launch_bounds__(256, 2)
void tail_kernel(const float* __restrict__ part, float* __restrict__ min_val,
                 const float* __restrict__ patch, const float* __restrict__ lib,
                 const bf16_t* __restrict__ lb,
                 const float* __restrict__ meanp, const float* __restrict__ stdp,
                 Scal* __restrict__ sc, float* __restrict__ wdist2,
                 float* __restrict__ out0, float* __restrict__ outmap) {
  __shared__ union {
    unsigned long long sl[768];   // top3
    float rs[40 * 40];            // resize halo
  } sm;
  __shared__ float redbuf[4];
  __shared__ int s_cnt;

  const int t = threadIdx.x;
  const int b = blockIdx.x;
  const int wave = t >> 6, lane = t & 63;

  // ---- P0: finalize (blocks 0..12 cover 3136 rows; coalesced column reads) ----
  {
    int row = b * 256 + t;
    if (row < N_PATCH) {
      float m = FLT_MAX_;
#pragma unroll 8
      for (int nt = 0; nt < NTILES; nt++)
        m = fminf(m, part[(size_t)nt * N_PATCH_PAD + row]);
      float v = sqrtf(m);
      min_val[row] = v;
      unsigned long long mp = (((unsigned long long)__float_as_uint(v)) << 32) |
                              (unsigned)(0xffffffffu - (unsigned)row);  // ties -> smaller row
      atomicMax(&sc->approx_max_pack, mp);
    }
  }
  grid_bar(&sc->bar[0], TAILB);

  // ---- P1: collect candidates (block 0; margin 0.05 ~ 10 sigma of bf16 dist noise) ----
  if (b == 0) {
    float amax = __uint_as_float((unsigned)(atomicMax(&sc->approx_max_pack, 0ULL) >> 32));
    for (int i = t; i < N_PATCH; i += 256) {
      if (min_val[i] >= amax - 0.05f) {
        int p = atomicAdd(&sc->cand_count, 1);
        if (p < 64) sc->cand[p] = i;
      }
    }
  }
  grid_bar(&sc->bar[1], TAILB);

  if (t == 0) s_cnt = atomicAdd(&sc->cand_count, 0);
  __syncthreads();
  int cnt = s_cnt; if (cnt > 64) cnt = 64;

  // ---- P2: tile-targeted exact refine. Block b owns ntile b (256 lib rows).
  {
    float mu = meanp[0], sd = stdp[0];
    for (int c = 0; c < cnt; c++) {
      int row = sc->cand[c];
      float pv_ = (t < NTILES) ? part[(size_t)t * N_PATCH_PAD + row] : FLT_MAX_;
      pv_ = wave_reduce_min(pv_);
      if (lane == 0) redbuf[wave] = pv_;
      __syncthreads();
      float bmin = fminf(fminf(redbuf[0], redbuf[1]), fminf(redbuf[2], redbuf[3]));
      __syncthreads();

      float4 pv[3];
#pragma unroll
      for (int k = 0; k < 3; k++) {
        float4 v = ((const float4*)(patch + (size_t)row * DIM))[lane + 64 * k];
        v.x = (v.x - mu) / sd; v.y = (v.y - mu) / sd;
        v.z = (v.z - mu) / sd; v.w = (v.w - mu) / sd;
        pv[k] = v;
      }
      int nt = b;
      float pmin = part[(size_t)nt * N_PATCH_PAD + row];   // uniform -> broadcast
      if (pmin <= bmin + D2_MARGIN) {
        unsigned long long best = ~0ULL;
        int jb = nt * 256 + wave * 64;
        for (int rr = 0; rr < 64; rr++) {
          int j = jb + rr;
          const float4* pl = (const float4*)(lib + (size_t)j * DIM);
          float acc = 0.f;
#pragma unroll
          for (int k = 0; k < 3; k++) {
            float4 l = pl[lane + 64 * k];
            float dx = pv[k].x - l.x, dy = pv[k].y - l.y;
            float dz = pv[k].z - l.z, dw = pv[k].w - l.w;
            acc += dx*dx + dy*dy + dz*dz + dw*dw;
          }
          acc = wave_reduce_sum(acc);
          unsigned long long pk = (((unsigned long long)__float_as_uint(acc)) << 32) | (unsigned)j;
          if (pk < best) best = pk;
        }
        if (lane == 0) atomicMin(&sc->cand_pack[c], best);
      }
    }
  }
  grid_bar(&sc->bar[2], TAILB);

  // ---- P3: wdist on bf16 lb (selection only; exact d's recomputed in P4a) ----
  {
    int srow_, ms; float ss_;
    wave_pick(sc, cnt, lane, &srow_, &ss_, &ms);
    float pm[12];
    const ushort4* pms = (const ushort4*)(lb + (size_t)ms * DIM);
#pragma unroll
    for (int k = 0; k < 3; k++) {
      ushort4 u = pms[lane + 64 * k];
      pm[k*4+0] = bf16u_to_f(u.x); pm[k*4+1] = bf16u_to_f(u.y);
      pm[k*4+2] = bf16u_to_f(u.z); pm[k*4+3] = bf16u_to_f(u.w);
    }
    int jbase = b * 256 + wave * 64;
    for (int rr = 0; rr < 64; rr += 2) {
      int j0 = jbase + rr, j1 = j0 + 1;
      const ushort4* r0 = (const ushort4*)(lb + (size_t)j0 * DIM);
      const ushort4* r1 = (const ushort4*)(lb + (size_t)j1 * DIM);
      float a0 = 0.f, a1 = 0.f;
#pragma unroll
      for (int k = 0; k < 3; k++) {
        ushort4 u0 = r0[lane + 64 * k];
        ushort4 u1 = r1[lane + 64 * k];
        float d;
        d = bf16u_to_f(u0.x) - pm[k*4+0]; a0 += d * d;
        d = bf16u_to_f(u0.y) - pm[k*4+1]; a0 += d * d;
        d = bf16u_to_f(u0.z) - pm[k*4+2]; a0 += d * d;
        d = bf16u_to_f(u0.w) - pm[k*4+3]; a0 += d * d;
        d = bf16u_to_f(u1.x) - pm[k*4+0]; a1 += d * d;
        d = bf16u_to_f(u1.y) - pm[k*4+1]; a1 += d * d;
        d = bf16u_to_f(u1.z) - pm[k*4+2]; a1 += d * d;
        d = bf16u_to_f(u1.w) - pm[k*4+3]; a1 += d * d;
      }
      a0 = wave_reduce_sum(a0);
      a1 = wave_reduce_sum(a1);
      if (lane == 0) { wdist2[j0] = a0; wdist2[j1] = a1; }
    }
  }
  grid_bar(&sc->bar[3], TAILB);

  // ---- P4a: top3 (approx selection) + exact scalar s (block 0) ----
  if (b == 0) {
    unsigned long long b0 = ~0ULL, b1 = ~0ULL, b2 = ~0ULL;
    for (int j = t; j < N_LIB; j += 256) {
      unsigned long long pk = (((unsigned long long)__float_as_uint(wdist2[j])) << 32) | (unsigned)j;
      if (pk < b0)      { b2 = b1; b1 = b0; b0 = pk; }
      else if (pk < b1) { b2 = b1; b1 = pk; }
      else if (pk < b2) { b2 = pk; }
    }
    sm.sl[t * 3 + 0] = b0; sm.sl[t * 3 + 1] = b1; sm.sl[t * 3 + 2] = b2;
    __syncthreads();
    if (t >= 64) return;

    unsigned long long c0 = ~0ULL, c1 = ~0ULL, c2 = ~0ULL;
#pragma unroll
    for (int e = 0; e < 12; e++) {
      unsigned long long pk = sm.sl[t * 12 + e];
      if (pk < c0)      { c2 = c1; c1 = c0; c0 = pk; }
      else if (pk < c1) { c2 = c1; c1 = pk; }
      else if (pk < c2) { c2 = pk; }
    }
    unsigned long long res1 = 0, res2 = 0;
#pragma unroll
    for (int r = 0; r < 3; r++) {
      unsigned long long m = c0;
#pragma unroll
      for (int s = 1; s < 64; s <<= 1) {
        unsigned long long o = shfl_xor_u64(m, s);
        if (o < m) m = o;
      }
      if (r == 1) res1 = m;
      if (r == 2) res2 = m;
      if (c0 == m) { c0 = c1; c1 = c2; c2 = ~0ULL; }
    }
    int nA = (int)(res1 & 0xffffffffu);   // 2nd nearest
    int nB = (int)(res2 & 0xffffffffu);   // 3rd nearest

    int srow, ms2; float sstar;
    wave_pick(sc, cnt, t, &srow, &sstar, &ms2);

    float mu = meanp[0], sd = stdp[0];
    float accA = 0.f, accB = 0.f;
#pragma unroll
    for (int k = 0; k < 3; k++) {
      float4 p4 = ((const float4*)(patch + (size_t)srow * DIM))[t + 64 * k];
      float4 a4 = ((const float4*)(lib + (size_t)nA * DIM))[t + 64 * k];
      float4 b4 = ((const float4*)(lib + (size_t)nB * DIM))[t + 64 * k];
      float px = (p4.x - mu) / sd, py = (p4.y - mu) / sd;
      float pz = (p4.z - mu) / sd, pw = (p4.w - mu) / sd;
      float dax = px - a4.x, day = py - a4.y, daz = pz - a4.z, daw = pw - a4.w;
      float dbx = px - b4.x, dby = py - b4.y, dbz = pz - b4.z, dbw = pw - b4.w;
      accA += dax*dax + day*day + daz*daz + daw*daw;
      accB += dbx*dbx + dby*dby + dbz*dbz + dbw*dbw;
    }
    accA = wave_reduce_sum(accA);
    accB = wave_reduce_sum(accB);
    if (t == 0) {
      float dsq = sqrtf((float)DIM);
      float d1 = sqrtf(accA), d2v = sqrtf(accB);
      float w = 1.0f - expf(sstar / dsq) / (expf(d1 / dsq) + expf(d2v / dsq));
      out0[0] = w * sstar;
    }
    return;
  }

  // ---- P4b: fused bilinear 56->224 + 9x9 blur (blocks 1..49) ----
  if (b > 49) return;
  {
    int tile = b - 1;
    int bx = tile % 7, by = tile / 7;
    int ox0 = bx * 32, oy0 = by * 32;

    for (int i = t; i < 1600; i += 256) {
      int ly = i / 40, lx = i % 40;
      int gy = oy0 - 4 + ly; gy = gy < 0 ? 0 : (gy > 223 ? 223 : gy);
      int gx = ox0 - 4 + lx; gx = gx < 0 ? 0 : (gx > 223 ? 223 : gx);
      float sy = fminf(fmaxf(0.25f * gy - 0.375f, 0.0f), 55.0f);
      float sx = fminf(fmaxf(0.25f * gx - 0.375f, 0.0f), 55.0f);
      int y0 = (int)sy; if (y0 > 54) y0 = 54;
      int x0 = (int)sx; if (x0 > 54) x0 = 54;
      float fy = sy - y0, fx = sx - x0;
      float v00 = min_val[y0*FM + x0],     v01 = min_val[y0*FM + x0 + 1];
      float v10 = min_val[(y0+1)*FM + x0], v11 = min_val[(y0+1)*FM + x0 + 1];
      float a = v00 + fx * (v01 - v00);
      float bb = v10 + fx * (v11 - v10);
      sm.rs[i] = a + fy * (bb - a);
    }
    __syncthreads();

    float g[9]; float gs = 0.f;
#pragma unroll
    for (int i = 0; i < 9; i++) { float tt = (float)(i - 4); g[i] = expf(-(tt*tt)/32.0f); gs += g[i]; }
#pragma unroll
    for (int i = 0; i < 9; i++) g[i] /= gs;

    for (int p = t; p < 1024; p += 256) {
      int y = oy0 + p / 32, x = ox0 + (p & 31);
      float acc = 0.f;
#pragma unroll
      for (int dy = 0; dy < 9; dy++) {
        int yy = y + dy - 4;
        yy = yy < 0 ? -yy : (yy > IMGSZ - 1 ? 2*(IMGSZ-1) - yy : yy);
        int lyy = yy - (oy0 - 4);
        float ra = 0.f;
#pragma unroll
        for (int dx = 0; dx < 9; dx++) {
          int xx = x + dx - 4;
          xx = xx < 0 ? -xx : (xx > IMGSZ - 1 ? 2*(IMGSZ-1) - xx : xx);
          ra += g[dx] * sm.rs[lyy * 40 + (xx - (ox0 - 4))];
        }
        acc += g[dy] * ra;
      }
      outmap[y * IMGSZ + x] = acc;
    }
  }
}

// ================================================= host
extern "C" void kernel_launch(void* const* d_in, const int* in_sizes, int n_in,
                              void* d_out, int out_size, void* d_ws, size_t ws_size,
                              hipStream_t stream) {
  const float* patch = (const float*)d_in[0];
  const float* lib   = (const float*)d_in[1];
  const float* meanp = (const float*)d_in[2];
  const float* stdp  = (const float*)d_in[3];
  float* out = (float*)d_out;

  char* ws = (char*)d_ws;
  size_t off = 0;
  auto alloc = [&](size_t bytes) -> void* {
    void* p = ws + off;
    off = (off + bytes + 255) & ~(size_t)255;
    return p;
  };
  bf16_t* pb      = (bf16_t*)alloc((size_t)N_PATCH_PAD * DIM * sizeof(bf16_t));
  bf16_t* lb      = (bf16_t*)alloc((size_t)N_LIB * DIM * sizeof(bf16_t));
  float* a2       = (float*)alloc(N_PATCH * sizeof(float));
  float* b2       = (float*)alloc(N_LIB * sizeof(float));
  float* part     = (float*)alloc((size_t)N_PATCH_PAD * NTILES * sizeof(float));
  float* min_val  = (float*)alloc(N_PATCH * sizeof(float));
  float* wdist2   = (float*)alloc(N_LIB * sizeof(float));
  Scal*  sc       = (Scal*)alloc(sizeof(Scal));

  prep_kernel<<<N_PATCH_PAD / 4 + N_LIB / 4, 256, 0, stream>>>(patch, lib, meanp, stdp,
                                                               pb, lb, a2, b2, sc);
  gemm_min_kernel<<<256, 512, 0, stream>>>(pb, lb, a2, b2, part);
  tail_kernel<<<TAILB, 256, 0, stream>>>(part, min_val, patch, lib, lb, meanp, stdp,
                                         sc, wdist2, out, out + 1);
}